// Round 9
// baseline (77.987 us; speedup 1.0000x reference)
//
#include <hip/hip_runtime.h>
#include <cstdint>

#define B 32
#define T 40
#define V 64
#define H 768
#define M 64
#define POS_D 7
#define NCODE 64
#define THREADS 384
#define SEGW 24                  // per-wave member-list capacity (6 waves)
#define NSTEP (B * T)            // 1280 step blocks (FIRST)
#define NBIN_BLKS (B * NCODE)    // 2048 bin blocks (after steps)
#define NTAIL B                  // 32 catch-all blocks

// ---------------------------------------------------------------------------
// Epilogue: out[bm] = agg + step_tab[sid] + LN(pos@W + b_pos).
// 384 threads enter (block-uniform); first 192 are active (4 cols each).
// ---------------------------------------------------------------------------
__device__ __forceinline__ void epilogue(
    int b, int m, float ax, float ay, float az, float aw,
    bool act, int col4,
    const float* __restrict__ pos_fts, const float* __restrict__ W_pos,
    const float* __restrict__ b_pos, const float* __restrict__ gamma,
    const float* __restrict__ beta, const int* __restrict__ step_ids,
    const float* __restrict__ step_tab, float* __restrict__ out,
    float* w1, float* w2)
{
    const int tid = threadIdx.x;
    const int wv = tid >> 6, lane = tid & 63;
    const int bm = b * M + m;

    float px = 0.f, py = 0.f, pz = 0.f, pw = 0.f;
    if (act) {
        float f[POS_D];
        #pragma unroll
        for (int d = 0; d < POS_D; ++d) f[d] = pos_fts[bm * POS_D + d];
        const float4 bp = *(const float4*)(b_pos + col4);
        px = bp.x; py = bp.y; pz = bp.z; pw = bp.w;
        #pragma unroll
        for (int d = 0; d < POS_D; ++d) {
            const float4 wv4 = *(const float4*)(W_pos + d * H + col4);
            px += f[d] * wv4.x; py += f[d] * wv4.y;
            pz += f[d] * wv4.z; pw += f[d] * wv4.w;
        }
    }

    float s1 = px + py + pz + pw;
    float s2 = px * px + py * py + pz * pz + pw * pw;
    #pragma unroll
    for (int off = 32; off > 0; off >>= 1) {
        s1 += __shfl_xor(s1, off);
        s2 += __shfl_xor(s2, off);
    }
    __syncthreads();                    // guard w1/w2 reuse across calls
    if (lane == 0) { w1[wv] = s1; w2[wv] = s2; }
    __syncthreads();
    s1 = w1[0] + w1[1] + w1[2] + w1[3] + w1[4] + w1[5];
    s2 = w2[0] + w2[1] + w2[2] + w2[3] + w2[4] + w2[5];
    const float mu = s1 * (1.0f / H);
    const float var = fmaxf(s2 * (1.0f / H) - mu * mu, 0.f);
    const float rs = rsqrtf(var + 1e-12f);

    if (act) {
        const float4 gm = *(const float4*)(gamma + col4);
        const float4 bt4 = *(const float4*)(beta + col4);
        const int sid = step_ids[bm];
        const float4 st = *(const float4*)(step_tab + (size_t)sid * H + col4);
        float4 o;
        o.x = ax + st.x + (px - mu) * rs * gm.x + bt4.x;
        o.y = ay + st.y + (py - mu) * rs * gm.y + bt4.y;
        o.z = az + st.z + (pz - mu) * rs * gm.z + bt4.z;
        o.w = aw + st.w + (pw - mu) * rs * gm.w + bt4.w;
        *(float4*)(out + (size_t)bm * H + col4) = o;
    }
}

// ---------------------------------------------------------------------------
// Single kernel, owner-writes-outputs, zero workspace.
//  [0, NSTEP):      step means (streaming, 2 rows/iter) — runs FIRST
//  [.., +NBIN_BLKS): unvisited-code bins (gather; L3-warm by then)
//  [.., +NTAIL):    catch-all (m==0 / out-of-range codes)
// ---------------------------------------------------------------------------
__global__ __launch_bounds__(THREADS) void fused_kernel(
    const float* __restrict__ emb, const int* __restrict__ lens,
    const int* __restrict__ cand, const int* __restrict__ tvp,
    const int* __restrict__ gvp, const int* __restrict__ step_ids,
    const float* __restrict__ pos_fts, const float* __restrict__ W_pos,
    const float* __restrict__ b_pos, const float* __restrict__ gamma,
    const float* __restrict__ beta, const float* __restrict__ step_tab,
    float* __restrict__ out)
{
    const int tid = threadIdx.x;
    const int blk = blockIdx.x;
    const int wv = tid >> 6, lane = tid & 63;
    const bool act = tid < 192;
    const int sub = act ? 0 : 1;              // row-parity group
    const int col4 = (act ? tid : tid - 192) * 4;

    __shared__ int tvp_s[T], gvp_s[M], lens_s[T];
    __shared__ int code_s, cnt_s;
    __shared__ int list_s[6 * SEGW];
    __shared__ int wcnt[6];
    __shared__ float comb[H];                 // odd-group partials (3 KB)
    __shared__ float w1[6], w2[6];

    if (blk < NSTEP) {
        // ================= step path: (b,t), streams its len-prefix ========
        const int bt = blk;
        const int b = bt / T, t = bt - b * T;
        if (tid < T) tvp_s[tid] = tvp[b * T + tid];
        if (tid < M) gvp_s[tid] = gvp[b * M + tid];
        __syncthreads();

        const int c = tvp_s[t];
        int lt = -1;
        #pragma unroll 8
        for (int tt = 0; tt < T; ++tt) if (tvp_s[tt] == c) lt = tt;
        if (lt != t) return;                  // another t owns this code
        bool any = false;
        #pragma unroll 8
        for (int m = 1; m < M; ++m) any |= (gvp_s[m] == c);
        if (!any) return;                     // no consumer

        const int len = lens[bt];
        const float* base = emb + (size_t)bt * V * H + col4;
        float ax = 0.f, ay = 0.f, az = 0.f, aw = 0.f;
        int v = 0;
        for (; v + 32 <= len; v += 32) {      // 16 loads in flight / thread
            #pragma unroll
            for (int u = 0; u < 16; ++u) {
                const float4 x = *(const float4*)(base + (size_t)(v + 2 * u + sub) * H);
                ax += x.x; ay += x.y; az += x.z; aw += x.w;
            }
        }
        for (; v + 16 <= len; v += 16) {
            #pragma unroll
            for (int u = 0; u < 8; ++u) {
                const float4 x = *(const float4*)(base + (size_t)(v + 2 * u + sub) * H);
                ax += x.x; ay += x.y; az += x.z; aw += x.w;
            }
        }
        for (; v + 8 <= len; v += 8) {
            #pragma unroll
            for (int u = 0; u < 4; ++u) {
                const float4 x = *(const float4*)(base + (size_t)(v + 2 * u + sub) * H);
                ax += x.x; ay += x.y; az += x.z; aw += x.w;
            }
        }
        for (; v + 2 <= len; v += 2) {
            const float4 x = *(const float4*)(base + (size_t)(v + sub) * H);
            ax += x.x; ay += x.y; az += x.z; aw += x.w;
        }
        if (v < len && sub == 0) {            // odd leftover row -> even group
            const float4 x = *(const float4*)(base + (size_t)v * H);
            ax += x.x; ay += x.y; az += x.z; aw += x.w;
        }
        // combine odd-group into even-group (fixed order -> deterministic)
        if (!act) { float4 o; o.x = ax; o.y = ay; o.z = az; o.w = aw;
                    *(float4*)(comb + col4) = o; }
        __syncthreads();
        if (act) {
            const float4 o = *(const float4*)(comb + col4);
            const float inv = 1.0f / (float)len;
            ax = (ax + o.x) * inv; ay = (ay + o.y) * inv;
            az = (az + o.z) * inv; aw = (aw + o.w) * inv;
        }
        for (int m = 1; m < M; ++m)
            if (gvp_s[m] == c)
                epilogue(b, m, ax, ay, az, aw, act, col4, pos_fts, W_pos, b_pos,
                         gamma, beta, step_ids, step_tab, out, w1, w2);
        return;
    }

    if (blk < NSTEP + NBIN_BLKS) {
        // ================= bin path: (b, rank) =============================
        const int bb = blk - NSTEP;
        const int b = bb >> 6, bin = bb & 63;

        if (tid < T) { tvp_s[tid] = tvp[b * T + tid]; lens_s[tid] = lens[b * T + tid]; }
        if (tid < M) gvp_s[tid] = gvp[b * M + tid];
        if (tid == 0) { code_s = -1; cnt_s = 0; }
        if (tid < 6) wcnt[tid] = 0;
        __syncthreads();

        if (tid < 64) {                       // wave 0 ranks needed codes
            const int c = tid;
            bool mention = false;
            #pragma unroll 8
            for (int mm = 0; mm < M; ++mm) mention |= (gvp_s[mm] == c);
            bool vis = false;
            #pragma unroll 8
            for (int t = 0; t < T; ++t) vis |= (tvp_s[t] == c);
            const bool needed = mention && !vis;
            const unsigned long long mask = __ballot(needed);
            const int pre = __popcll(mask & ((1ull << c) - 1ull));
            if (needed && pre == bin) code_s = c;
        }
        __syncthreads();

        const int code = code_s;              // block-uniform
        if (code < 0) return;                 // empty bin

        const int* cb = cand + b * T * V;
        int local = 0;
        for (int i = tid; i < T * V; i += THREADS) local += (cb[i] == code);
        #pragma unroll
        for (int off = 32; off; off >>= 1) local += __shfl_xor(local, off);
        if (lane == 0) atomicAdd(&cnt_s, local);

        // member list: wave wv owns t = wv, wv+6, ...; fixed order
        int myn = 0;
        for (int t = wv; t < T; t += 6) {
            const int cc = cb[t * V + lane];
            const bool ok = (lane < lens_s[t]) && (cc == code);
            const unsigned long long mk = __ballot(ok);
            if (ok) {
                const int pos = myn + __popcll(mk & ((1ull << lane) - 1ull));
                if (pos < SEGW) list_s[wv * SEGW + pos] = t * V + lane;
            }
            myn += __popcll(mk);
        }
        if (lane == 0) wcnt[wv] = min(myn, SEGW);
        __syncthreads();

        // gather: parity-split entries within each segment (fixed order)
        float ax = 0.f, ay = 0.f, az = 0.f, aw = 0.f;
        const float* eb = emb + (size_t)b * T * V * H + col4;
        for (int ww = 0; ww < 6; ++ww) {
            const int n = wcnt[ww];
            #pragma unroll 4
            for (int k = sub; k < n; k += 2) {
                const float4 x = *(const float4*)(eb + (size_t)list_s[ww * SEGW + k] * H);
                ax += x.x; ay += x.y; az += x.z; aw += x.w;
            }
        }
        if (!act) { float4 o; o.x = ax; o.y = ay; o.z = az; o.w = aw;
                    *(float4*)(comb + col4) = o; }
        __syncthreads();
        if (act) {
            const float4 o = *(const float4*)(comb + col4);
            const float inv = 1.0f / fmaxf((float)cnt_s, 1.0f);
            ax = (ax + o.x) * inv; ay = (ay + o.y) * inv;
            az = (az + o.z) * inv; aw = (aw + o.w) * inv;
        }
        for (int m = 1; m < M; ++m)
            if (gvp_s[m] == code)
                epilogue(b, m, ax, ay, az, aw, act, col4, pos_fts, W_pos, b_pos,
                         gamma, beta, step_ids, step_tab, out, w1, w2);
        return;
    }

    // ================= catch-all: one block per batch ======================
    {
        const int b = blk - (NSTEP + NBIN_BLKS);
        if (tid < M) gvp_s[tid] = gvp[b * M + tid];
        __syncthreads();
        for (int m = 0; m < M; ++m) {
            const int g = gvp_s[m];
            const bool handled = (m != 0) && (g >= 0) && (g < NCODE);
            if (!handled)
                epilogue(b, m, 0.f, 0.f, 0.f, 0.f, act, col4, pos_fts, W_pos,
                         b_pos, gamma, beta, step_ids, step_tab, out, w1, w2);
        }
    }
}

// ---------------------------------------------------------------------------
extern "C" void kernel_launch(void* const* d_in, const int* in_sizes, int n_in,
                              void* d_out, int out_size, void* d_ws, size_t ws_size,
                              hipStream_t stream)
{
    const float* emb      = (const float*)d_in[2];
    const int*   vp_lens  = (const int*)d_in[3];
    const int*   tvp      = (const int*)d_in[4];
    const int*   cand     = (const int*)d_in[5];
    const int*   gvp      = (const int*)d_in[6];
    const int*   step_ids = (const int*)d_in[7];
    const float* pos_fts  = (const float*)d_in[8];
    const float* W_pos    = (const float*)d_in[10];
    const float* b_pos    = (const float*)d_in[11];
    const float* gamma    = (const float*)d_in[12];
    const float* beta     = (const float*)d_in[13];
    const float* step_tab = (const float*)d_in[14];
    float* out = (float*)d_out;

    fused_kernel<<<NSTEP + NBIN_BLKS + NTAIL, THREADS, 0, stream>>>(
        emb, vp_lens, cand, tvp, gvp, step_ids, pos_fts,
        W_pos, b_pos, gamma, beta, step_tab, out);
}

// Round 10
// 53.132 us; speedup vs baseline: 1.4678x; 1.4678x over previous
//
#include <hip/hip_runtime.h>
#include <cstdint>

#define B 32
#define T 40
#define V 64
#define H 768
#define M 64
#define POS_D 7
#define NCODE 64
#define SEG 48                   // per-wave member-list segment
#define NSTEP (B * T)            // 1280 step blocks — run FIRST
#define NBIN_BLKS (B * NCODE)    // 2048 bin blocks (empties exit immediately)
#define NTAIL B                  // 32 catch-all blocks (m==0 / invalid code)

// ---------------------------------------------------------------------------
// Epilogue for one output (b,m): out = agg + step_table[sid] + LN(pos@W + b).
// Must be called block-uniformly. agg held in registers (4 floats / thread).
// ---------------------------------------------------------------------------
__device__ __forceinline__ void epilogue(
    int b, int m, float ax, float ay, float az, float aw,
    const float* __restrict__ pos_fts, const float* __restrict__ W_pos,
    const float* __restrict__ b_pos, const float* __restrict__ gamma,
    const float* __restrict__ beta, const int* __restrict__ step_ids,
    const float* __restrict__ step_tab, float* __restrict__ out,
    float* w1, float* w2)
{
    const int tid = threadIdx.x;
    const int hl = tid * 4;
    const int bm = b * M + m;

    float f[POS_D];
    #pragma unroll
    for (int d = 0; d < POS_D; ++d) f[d] = pos_fts[bm * POS_D + d];
    const float4 bp = *(const float4*)(b_pos + hl);
    float px = bp.x, py = bp.y, pz = bp.z, pw = bp.w;
    #pragma unroll
    for (int d = 0; d < POS_D; ++d) {
        const float4 wv4 = *(const float4*)(W_pos + d * H + hl);
        px += f[d] * wv4.x; py += f[d] * wv4.y;
        pz += f[d] * wv4.z; pw += f[d] * wv4.w;
    }

    float s1 = px + py + pz + pw;
    float s2 = px * px + py * py + pz * pz + pw * pw;
    #pragma unroll
    for (int off = 32; off > 0; off >>= 1) {
        s1 += __shfl_xor(s1, off);
        s2 += __shfl_xor(s2, off);
    }
    __syncthreads();                       // guard w1/w2 reuse across calls
    const int wv = tid >> 6;
    if ((tid & 63) == 0) { w1[wv] = s1; w2[wv] = s2; }
    __syncthreads();
    s1 = w1[0] + w1[1] + w1[2];
    s2 = w2[0] + w2[1] + w2[2];
    const float mu = s1 * (1.0f / H);
    const float var = fmaxf(s2 * (1.0f / H) - mu * mu, 0.f);
    const float rs = rsqrtf(var + 1e-12f);

    const float4 gm = *(const float4*)(gamma + hl);
    const float4 bt4 = *(const float4*)(beta + hl);
    const int sid = step_ids[bm];
    const float4 st = *(const float4*)(step_tab + (size_t)sid * H + hl);

    float4 o;
    o.x = ax + st.x + (px - mu) * rs * gm.x + bt4.x;
    o.y = ay + st.y + (py - mu) * rs * gm.y + bt4.y;
    o.z = az + st.z + (pz - mu) * rs * gm.z + bt4.z;
    o.w = aw + st.w + (pw - mu) * rs * gm.w + bt4.w;
    *(float4*)(out + (size_t)bm * H + hl) = o;
}

// ---------------------------------------------------------------------------
// Single kernel, three block classes, disjoint outputs, zero workspace:
//  [0, NSTEP):        step means — stream + mean + epilogue(s); runs FIRST
//  [.., +NBIN_BLKS):  unvisited-code bins — L3-warm gather + mean + epilogue
//  [.., +NTAIL):      catch-all — m==0 or invalid code -> agg = 0
// ---------------------------------------------------------------------------
__global__ __launch_bounds__(192) void fused_kernel(
    const float* __restrict__ emb, const int* __restrict__ lens,
    const int* __restrict__ cand, const int* __restrict__ tvp,
    const int* __restrict__ gvp, const int* __restrict__ step_ids,
    const float* __restrict__ pos_fts, const float* __restrict__ W_pos,
    const float* __restrict__ b_pos, const float* __restrict__ gamma,
    const float* __restrict__ beta, const float* __restrict__ step_tab,
    float* __restrict__ out)
{
    const int tid = threadIdx.x;
    const int blk = blockIdx.x;
    const int w = tid >> 6, lane = tid & 63;

    __shared__ int tvp_s[T], gvp_s[M], lens_s[T];
    __shared__ int code_s, cnt_s;
    __shared__ int list_s[3 * SEG];
    __shared__ int wcnt[3];
    __shared__ float w1[3], w2[3];

    if (blk < NSTEP) {
        // ================= step path: (b, t) =================
        const int bt = blk;
        const int b = bt / T, t = bt - b * T;

        if (tid < T) tvp_s[tid] = tvp[b * T + tid];
        if (tid < M) gvp_s[tid] = gvp[b * M + tid];
        __syncthreads();

        const int c = tvp_s[t];
        int lt = -1;
        #pragma unroll 8
        for (int tt = 0; tt < T; ++tt) if (tvp_s[tt] == c) lt = tt;
        if (lt != t) return;               // another block owns this code

        bool any = false;
        #pragma unroll 8
        for (int m = 1; m < M; ++m) any |= (gvp_s[m] == c);
        if (!any) return;                  // no consumer

        const int len = lens[bt];
        const float* base = emb + (size_t)bt * V * H + tid * 4;
        float ax = 0.f, ay = 0.f, az = 0.f, aw = 0.f;
        int v = 0;
        for (; v + 16 <= len; v += 16) {
            #pragma unroll
            for (int u = 0; u < 16; ++u) {
                const float4 x = *(const float4*)(base + (size_t)(v + u) * H);
                ax += x.x; ay += x.y; az += x.z; aw += x.w;
            }
        }
        #pragma unroll 4
        for (; v < len; ++v) {
            const float4 x = *(const float4*)(base + (size_t)v * H);
            ax += x.x; ay += x.y; az += x.z; aw += x.w;
        }
        const float inv = 1.0f / (float)len;
        ax *= inv; ay *= inv; az *= inv; aw *= inv;

        for (int m = 1; m < M; ++m)
            if (gvp_s[m] == c)
                epilogue(b, m, ax, ay, az, aw, pos_fts, W_pos, b_pos,
                         gamma, beta, step_ids, step_tab, out, w1, w2);
        return;
    }

    if (blk < NSTEP + NBIN_BLKS) {
        // ================= bin path: (b, rank) =================
        const int bb = blk - NSTEP;
        const int b = bb >> 6, bin = bb & 63;

        if (tid < T) { tvp_s[tid] = tvp[b * T + tid]; lens_s[tid] = lens[b * T + tid]; }
        if (tid < M) gvp_s[tid] = gvp[b * M + tid];
        if (tid == 0) { code_s = -1; cnt_s = 0; }
        if (tid < 3) wcnt[tid] = 0;
        __syncthreads();

        // wave 0: rank the needed (mentioned && unvisited) codes
        if (tid < 64) {
            const int c = tid;
            bool mention = false;
            #pragma unroll 8
            for (int mm = 0; mm < M; ++mm) mention |= (gvp_s[mm] == c);
            bool vis = false;
            #pragma unroll 8
            for (int t = 0; t < T; ++t) vis |= (tvp_s[t] == c);
            const bool needed = mention && !vis;
            const unsigned long long mask = __ballot(needed);
            const int pre = __popcll(mask & ((1ull << c) - 1ull));
            if (needed && pre == bin) code_s = c;
        }
        __syncthreads();

        const int code = code_s;           // block-uniform
        if (code < 0) return;              // empty bin

        // unmasked count of cand == code
        const int* cb = cand + b * T * V;
        int local = 0;
        for (int i = tid; i < T * V; i += 192) local += (cb[i] == code);
        #pragma unroll
        for (int off = 32; off; off >>= 1) local += __shfl_xor(local, off);
        if (lane == 0) atomicAdd(&cnt_s, local);

        // member list (len-masked), wave w owns t = w, w+3, ...; fixed order
        int myn = 0;
        for (int t = w; t < T; t += 3) {
            const int cc = cb[t * V + lane];
            const bool ok = (lane < lens_s[t]) && (cc == code);
            const unsigned long long mk = __ballot(ok);
            if (ok) {
                const int pos = myn + __popcll(mk & ((1ull << lane) - 1ull));
                if (pos < SEG) list_s[w * SEG + pos] = t * V + lane;
            }
            myn += __popcll(mk);
        }
        if (lane == 0) wcnt[w] = min(myn, SEG);
        __syncthreads();

        float ax = 0.f, ay = 0.f, az = 0.f, aw = 0.f;
        const float* eb = emb + (size_t)b * T * V * H + tid * 4;
        for (int ww = 0; ww < 3; ++ww) {   // fixed segment order
            const int n = wcnt[ww];
            #pragma unroll 8
            for (int k = 0; k < n; ++k) {
                const int tvx = list_s[ww * SEG + k];
                const float4 x = *(const float4*)(eb + (size_t)tvx * H);
                ax += x.x; ay += x.y; az += x.z; aw += x.w;
            }
        }
        const float inv = 1.0f / fmaxf((float)cnt_s, 1.0f);
        ax *= inv; ay *= inv; az *= inv; aw *= inv;

        for (int m = 1; m < M; ++m)
            if (gvp_s[m] == code)
                epilogue(b, m, ax, ay, az, aw, pos_fts, W_pos, b_pos,
                         gamma, beta, step_ids, step_tab, out, w1, w2);
        return;
    }

    // ================= catch-all path: one block per batch =================
    {
        const int b = blk - (NSTEP + NBIN_BLKS);
        if (tid < M) gvp_s[tid] = gvp[b * M + tid];
        __syncthreads();
        for (int m = 0; m < M; ++m) {
            const int g = gvp_s[m];
            const bool handled = (m != 0) && (g >= 0) && (g < NCODE);
            if (!handled)
                epilogue(b, m, 0.f, 0.f, 0.f, 0.f, pos_fts, W_pos, b_pos,
                         gamma, beta, step_ids, step_tab, out, w1, w2);
        }
    }
}

// ---------------------------------------------------------------------------
extern "C" void kernel_launch(void* const* d_in, const int* in_sizes, int n_in,
                              void* d_out, int out_size, void* d_ws, size_t ws_size,
                              hipStream_t stream)
{
    const float* emb      = (const float*)d_in[2];
    const int*   vp_lens  = (const int*)d_in[3];
    const int*   tvp      = (const int*)d_in[4];
    const int*   cand     = (const int*)d_in[5];
    const int*   gvp      = (const int*)d_in[6];
    const int*   step_ids = (const int*)d_in[7];
    const float* pos_fts  = (const float*)d_in[8];
    const float* W_pos    = (const float*)d_in[10];
    const float* b_pos    = (const float*)d_in[11];
    const float* gamma    = (const float*)d_in[12];
    const float* beta     = (const float*)d_in[13];
    const float* step_tab = (const float*)d_in[14];
    float* out = (float*)d_out;

    fused_kernel<<<NSTEP + NBIN_BLKS + NTAIL, 192, 0, stream>>>(
        emb, vp_lens, cand, tvp, gvp, step_ids, pos_fts,
        W_pos, b_pos, gamma, beta, step_tab, out);
}

// Round 12
// 48.820 us; speedup vs baseline: 1.5975x; 1.0883x over previous
//
#include <hip/hip_runtime.h>
#include <cstdint>

#define B 32
#define T 40
#define V 64
#define H 768
#define M 64
#define POS_D 7
#define NCODE 64
#define SEG 48                   // per-wave member-list segment (bins)
#define NBIN_BLKS (B * NCODE)    // 2048 bin blocks — run FIRST (proven R8/R10)
#define NSTEP (B * T)            // 1280 items
#define NSTEP_BLKS (NSTEP * 2)   // 2560 half-column step blocks
#define NTAIL B                  // 32 catch-all blocks
#define HALFC 384                // H/2 columns per step block

// ---------------------------------------------------------------------------
// Full-row epilogue (bins, catch-all): out = agg + step_tab + LN(pos@W + b).
// ---------------------------------------------------------------------------
__device__ __forceinline__ void epilogue(
    int b, int m, float ax, float ay, float az, float aw,
    const float* __restrict__ pos_fts, const float* __restrict__ W_pos,
    const float* __restrict__ b_pos, const float* __restrict__ gamma,
    const float* __restrict__ beta, const int* __restrict__ step_ids,
    const float* __restrict__ step_tab, float* __restrict__ out,
    float* w1, float* w2)
{
    const int tid = threadIdx.x;
    const int hl = tid * 4;
    const int bm = b * M + m;

    float f[POS_D];
    #pragma unroll
    for (int d = 0; d < POS_D; ++d) f[d] = pos_fts[bm * POS_D + d];
    const float4 bp = *(const float4*)(b_pos + hl);
    float px = bp.x, py = bp.y, pz = bp.z, pw = bp.w;
    #pragma unroll
    for (int d = 0; d < POS_D; ++d) {
        const float4 wv4 = *(const float4*)(W_pos + d * H + hl);
        px += f[d] * wv4.x; py += f[d] * wv4.y;
        pz += f[d] * wv4.z; pw += f[d] * wv4.w;
    }

    float s1 = px + py + pz + pw;
    float s2 = px * px + py * py + pz * pz + pw * pw;
    #pragma unroll
    for (int off = 32; off > 0; off >>= 1) {
        s1 += __shfl_xor(s1, off);
        s2 += __shfl_xor(s2, off);
    }
    __syncthreads();                       // guard w1/w2 reuse across calls
    const int wv = tid >> 6;
    if ((tid & 63) == 0) { w1[wv] = s1; w2[wv] = s2; }
    __syncthreads();
    s1 = w1[0] + w1[1] + w1[2];
    s2 = w2[0] + w2[1] + w2[2];
    const float mu = s1 * (1.0f / H);
    const float var = fmaxf(s2 * (1.0f / H) - mu * mu, 0.f);
    const float rs = rsqrtf(var + 1e-12f);

    const float4 gm = *(const float4*)(gamma + hl);
    const float4 bt4 = *(const float4*)(beta + hl);
    const int sid = step_ids[bm];
    const float4 st = *(const float4*)(step_tab + (size_t)sid * H + hl);

    float4 o;
    o.x = ax + st.x + (px - mu) * rs * gm.x + bt4.x;
    o.y = ay + st.y + (py - mu) * rs * gm.y + bt4.y;
    o.z = az + st.z + (pz - mu) * rs * gm.z + bt4.z;
    o.w = aw + st.w + (pw - mu) * rs * gm.w + bt4.w;
    *(float4*)(out + (size_t)bm * H + hl) = o;
}

// ---------------------------------------------------------------------------
// Half-column epilogue (step path): stats computed over the FULL row
// (bitwise identical in both half-blocks); writes only columns
// [half*384, half*384+384) with the block's streamed agg (float2/thread).
// ---------------------------------------------------------------------------
__device__ __forceinline__ void epilogue_half(
    int b, int m, float ax, float ay, int half,
    const float* __restrict__ pos_fts, const float* __restrict__ W_pos,
    const float* __restrict__ b_pos, const float* __restrict__ gamma,
    const float* __restrict__ beta, const int* __restrict__ step_ids,
    const float* __restrict__ step_tab, float* __restrict__ out,
    float* w1, float* w2)
{
    const int tid = threadIdx.x;
    const int hl = tid * 4;                // stats columns (full row)
    const int bm = b * M + m;

    float f[POS_D];
    #pragma unroll
    for (int d = 0; d < POS_D; ++d) f[d] = pos_fts[bm * POS_D + d];
    const float4 bp = *(const float4*)(b_pos + hl);
    float px = bp.x, py = bp.y, pz = bp.z, pw = bp.w;
    #pragma unroll
    for (int d = 0; d < POS_D; ++d) {
        const float4 wv4 = *(const float4*)(W_pos + d * H + hl);
        px += f[d] * wv4.x; py += f[d] * wv4.y;
        pz += f[d] * wv4.z; pw += f[d] * wv4.w;
    }

    float s1 = px + py + pz + pw;
    float s2 = px * px + py * py + pz * pz + pw * pw;
    #pragma unroll
    for (int off = 32; off > 0; off >>= 1) {
        s1 += __shfl_xor(s1, off);
        s2 += __shfl_xor(s2, off);
    }
    __syncthreads();                       // guard w1/w2 reuse across calls
    const int wv = tid >> 6;
    if ((tid & 63) == 0) { w1[wv] = s1; w2[wv] = s2; }
    __syncthreads();
    s1 = w1[0] + w1[1] + w1[2];
    s2 = w2[0] + w2[1] + w2[2];
    const float mu = s1 * (1.0f / H);
    const float var = fmaxf(s2 * (1.0f / H) - mu * mu, 0.f);
    const float rs = rsqrtf(var + 1e-12f);

    // output: two columns at oc (recompute pos there; same op order -> bitwise)
    const int oc = half * HALFC + tid * 2;
    const float2 bp2 = *(const float2*)(b_pos + oc);
    float p0 = bp2.x, p1 = bp2.y;
    #pragma unroll
    for (int d = 0; d < POS_D; ++d) {
        const float2 wv2 = *(const float2*)(W_pos + d * H + oc);
        p0 += f[d] * wv2.x; p1 += f[d] * wv2.y;
    }
    const float2 g2 = *(const float2*)(gamma + oc);
    const float2 b2 = *(const float2*)(beta + oc);
    const int sid = step_ids[bm];
    const float2 st2 = *(const float2*)(step_tab + (size_t)sid * H + oc);

    float2 o;
    o.x = ax + st2.x + (p0 - mu) * rs * g2.x + b2.x;
    o.y = ay + st2.y + (p1 - mu) * rs * g2.y + b2.y;
    *(float2*)(out + (size_t)bm * H + oc) = o;
}

// ---------------------------------------------------------------------------
// Single kernel, owner-writes-outputs, zero workspace:
//  [0, NBIN_BLKS):     unvisited-code bins (cold gathers, backfilled)
//  [.., +NSTEP_BLKS):  step means, HALF-COLUMN blocks (no combine needed)
//  [.., +NTAIL):       catch-all (m==0 / invalid code)
// ---------------------------------------------------------------------------
__global__ __launch_bounds__(192) void fused_kernel(
    const float* __restrict__ emb, const int* __restrict__ lens,
    const int* __restrict__ cand, const int* __restrict__ tvp,
    const int* __restrict__ gvp, const int* __restrict__ step_ids,
    const float* __restrict__ pos_fts, const float* __restrict__ W_pos,
    const float* __restrict__ b_pos, const float* __restrict__ gamma,
    const float* __restrict__ beta, const float* __restrict__ step_tab,
    float* __restrict__ out)
{
    const int tid = threadIdx.x;
    const int blk = blockIdx.x;
    const int w = tid >> 6, lane = tid & 63;

    __shared__ int tvp_s[T], gvp_s[M], lens_s[T];
    __shared__ int code_s, cnt_s;
    __shared__ int list_s[3 * SEG];
    __shared__ int wcnt[3];
    __shared__ float w1[3], w2[3];

    if (blk < NBIN_BLKS) {
        // ================= bin path: (b, rank) — identical to R8 ===========
        const int b = blk >> 6, bin = blk & 63;

        if (tid < T) { tvp_s[tid] = tvp[b * T + tid]; lens_s[tid] = lens[b * T + tid]; }
        if (tid < M) gvp_s[tid] = gvp[b * M + tid];
        if (tid == 0) { code_s = -1; cnt_s = 0; }
        if (tid < 3) wcnt[tid] = 0;
        __syncthreads();

        if (tid < 64) {
            const int c = tid;
            bool mention = false;
            #pragma unroll 8
            for (int mm = 0; mm < M; ++mm) mention |= (gvp_s[mm] == c);
            bool vis = false;
            #pragma unroll 8
            for (int t = 0; t < T; ++t) vis |= (tvp_s[t] == c);
            const bool needed = mention && !vis;
            const unsigned long long mask = __ballot(needed);
            const int pre = __popcll(mask & ((1ull << c) - 1ull));
            if (needed && pre == bin) code_s = c;
        }
        __syncthreads();

        const int code = code_s;           // block-uniform
        if (code < 0) return;              // empty bin

        const int* cb = cand + b * T * V;
        int local = 0;
        for (int i = tid; i < T * V; i += 192) local += (cb[i] == code);
        #pragma unroll
        for (int off = 32; off; off >>= 1) local += __shfl_xor(local, off);
        if (lane == 0) atomicAdd(&cnt_s, local);

        int myn = 0;
        for (int t = w; t < T; t += 3) {
            const int cc = cb[t * V + lane];
            const bool ok = (lane < lens_s[t]) && (cc == code);
            const unsigned long long mk = __ballot(ok);
            if (ok) {
                const int pos = myn + __popcll(mk & ((1ull << lane) - 1ull));
                if (pos < SEG) list_s[w * SEG + pos] = t * V + lane;
            }
            myn += __popcll(mk);
        }
        if (lane == 0) wcnt[w] = min(myn, SEG);
        __syncthreads();

        float ax = 0.f, ay = 0.f, az = 0.f, aw = 0.f;
        const float* eb = emb + (size_t)b * T * V * H + tid * 4;
        for (int ww = 0; ww < 3; ++ww) {   // fixed segment order
            const int n = wcnt[ww];
            #pragma unroll 8
            for (int k = 0; k < n; ++k) {
                const int tvx = list_s[ww * SEG + k];
                const float4 x = *(const float4*)(eb + (size_t)tvx * H);
                ax += x.x; ay += x.y; az += x.z; aw += x.w;
            }
        }
        const float inv = 1.0f / fmaxf((float)cnt_s, 1.0f);
        ax *= inv; ay *= inv; az *= inv; aw *= inv;

        for (int m = 1; m < M; ++m)
            if (gvp_s[m] == code)
                epilogue(b, m, ax, ay, az, aw, pos_fts, W_pos, b_pos,
                         gamma, beta, step_ids, step_tab, out, w1, w2);
        return;
    }

    if (blk < NBIN_BLKS + NSTEP_BLKS) {
        // ================= step path: (b, t, column-half) ==================
        const int idx = blk - NBIN_BLKS;
        const int bt = idx >> 1, half = idx & 1;
        const int b = bt / T, t = bt - b * T;

        if (tid < T) tvp_s[tid] = tvp[b * T + tid];
        if (tid < M) gvp_s[tid] = gvp[b * M + tid];
        __syncthreads();

        const int c = tvp_s[t];
        int lt = -1;
        #pragma unroll 8
        for (int tt = 0; tt < T; ++tt) if (tvp_s[tt] == c) lt = tt;
        if (lt != t) return;               // another t owns this code
        bool any = false;
        #pragma unroll 8
        for (int m = 1; m < M; ++m) any |= (gvp_s[m] == c);
        if (!any) return;                  // no consumer

        const int len = lens[bt];
        const float* base = emb + (size_t)bt * V * H + half * HALFC + tid * 2;
        float ax = 0.f, ay = 0.f;
        int v = 0;
        for (; v + 16 <= len; v += 16) {   // 16 float2 loads in flight
            #pragma unroll
            for (int u = 0; u < 16; ++u) {
                const float2 x = *(const float2*)(base + (size_t)(v + u) * H);
                ax += x.x; ay += x.y;
            }
        }
        #pragma unroll 4
        for (; v < len; ++v) {
            const float2 x = *(const float2*)(base + (size_t)v * H);
            ax += x.x; ay += x.y;
        }
        const float inv = 1.0f / (float)len;
        ax *= inv; ay *= inv;

        for (int m = 1; m < M; ++m)
            if (gvp_s[m] == c)
                epilogue_half(b, m, ax, ay, half, pos_fts, W_pos, b_pos,
                              gamma, beta, step_ids, step_tab, out, w1, w2);
        return;
    }

    // ================= catch-all path: one block per batch =================
    {
        const int b = blk - (NBIN_BLKS + NSTEP_BLKS);
        if (tid < M) gvp_s[tid] = gvp[b * M + tid];
        __syncthreads();
        for (int m = 0; m < M; ++m) {
            const int g = gvp_s[m];
            const bool handled = (m != 0) && (g >= 0) && (g < NCODE);
            if (!handled)
                epilogue(b, m, 0.f, 0.f, 0.f, 0.f, pos_fts, W_pos, b_pos,
                         gamma, beta, step_ids, step_tab, out, w1, w2);
        }
    }
}

// ---------------------------------------------------------------------------
extern "C" void kernel_launch(void* const* d_in, const int* in_sizes, int n_in,
                              void* d_out, int out_size, void* d_ws, size_t ws_size,
                              hipStream_t stream)
{
    const float* emb      = (const float*)d_in[2];
    const int*   vp_lens  = (const int*)d_in[3];
    const int*   tvp      = (const int*)d_in[4];
    const int*   cand     = (const int*)d_in[5];
    const int*   gvp      = (const int*)d_in[6];
    const int*   step_ids = (const int*)d_in[7];
    const float* pos_fts  = (const float*)d_in[8];
    const float* W_pos    = (const float*)d_in[10];
    const float* b_pos    = (const float*)d_in[11];
    const float* gamma    = (const float*)d_in[12];
    const float* beta     = (const float*)d_in[13];
    const float* step_tab = (const float*)d_in[14];
    float* out = (float*)d_out;

    fused_kernel<<<NBIN_BLKS + NSTEP_BLKS + NTAIL, 192, 0, stream>>>(
        emb, vp_lens, cand, tvp, gvp, step_ids, pos_fts,
        W_pos, b_pos, gamma, beta, step_tab, out);
}

// Round 13
// 44.821 us; speedup vs baseline: 1.7400x; 1.0892x over previous
//
#include <hip/hip_runtime.h>
#include <cstdint>

#define B 32
#define T 40
#define V 64
#define H 768
#define M 64
#define POS_D 7
#define NCODE 64
#define SEG 48                   // per-wave member-list segment
#define NBIN_BLKS (B * NCODE)    // 2048 bin blocks (logical ids [0, 2048))
#define NSTEP (B * T)            // 1280 step blocks (logical [2048, 3328))
#define NMAIN (NBIN_BLKS + NSTEP) // 3328 = 13 * 256, interleaved 8 bins : 5 steps
#define NTAIL B                  // 32 catch-all blocks (m==0 / invalid code)

// ---------------------------------------------------------------------------
// Epilogue for one output (b,m): out = agg + step_table[sid] + LN(pos@W + b).
// Must be called block-uniformly. agg held in registers (4 floats / thread).
// ---------------------------------------------------------------------------
__device__ __forceinline__ void epilogue(
    int b, int m, float ax, float ay, float az, float aw,
    const float* __restrict__ pos_fts, const float* __restrict__ W_pos,
    const float* __restrict__ b_pos, const float* __restrict__ gamma,
    const float* __restrict__ beta, const int* __restrict__ step_ids,
    const float* __restrict__ step_tab, float* __restrict__ out,
    float* w1, float* w2)
{
    const int tid = threadIdx.x;
    const int hl = tid * 4;
    const int bm = b * M + m;

    float f[POS_D];
    #pragma unroll
    for (int d = 0; d < POS_D; ++d) f[d] = pos_fts[bm * POS_D + d];
    const float4 bp = *(const float4*)(b_pos + hl);
    float px = bp.x, py = bp.y, pz = bp.z, pw = bp.w;
    #pragma unroll
    for (int d = 0; d < POS_D; ++d) {
        const float4 wv4 = *(const float4*)(W_pos + d * H + hl);
        px += f[d] * wv4.x; py += f[d] * wv4.y;
        pz += f[d] * wv4.z; pw += f[d] * wv4.w;
    }

    float s1 = px + py + pz + pw;
    float s2 = px * px + py * py + pz * pz + pw * pw;
    #pragma unroll
    for (int off = 32; off > 0; off >>= 1) {
        s1 += __shfl_xor(s1, off);
        s2 += __shfl_xor(s2, off);
    }
    __syncthreads();                       // guard w1/w2 reuse across calls
    const int wv = tid >> 6;
    if ((tid & 63) == 0) { w1[wv] = s1; w2[wv] = s2; }
    __syncthreads();
    s1 = w1[0] + w1[1] + w1[2];
    s2 = w2[0] + w2[1] + w2[2];
    const float mu = s1 * (1.0f / H);
    const float var = fmaxf(s2 * (1.0f / H) - mu * mu, 0.f);
    const float rs = rsqrtf(var + 1e-12f);

    const float4 gm = *(const float4*)(gamma + hl);
    const float4 bt4 = *(const float4*)(beta + hl);
    const int sid = step_ids[bm];
    const float4 st = *(const float4*)(step_tab + (size_t)sid * H + hl);

    float4 o;
    o.x = ax + st.x + (px - mu) * rs * gm.x + bt4.x;
    o.y = ay + st.y + (py - mu) * rs * gm.y + bt4.y;
    o.z = az + st.z + (pz - mu) * rs * gm.z + bt4.z;
    o.w = aw + st.w + (pw - mu) * rs * gm.w + bt4.w;
    *(float4*)(out + (size_t)bm * H + hl) = o;
}

// ---------------------------------------------------------------------------
// Single kernel, owner-writes-outputs, zero workspace. Logical block classes
// (identical to R8) are INTERLEAVED in dispatch order 8 bins : 5 steps per
// 13-block group, so every residency window mixes latency-bound bin blocks
// under BW-bound step blocks (no cold-gather lead-in phase).
// ---------------------------------------------------------------------------
__global__ __launch_bounds__(192) void fused_kernel(
    const float* __restrict__ emb, const int* __restrict__ lens,
    const int* __restrict__ cand, const int* __restrict__ tvp,
    const int* __restrict__ gvp, const int* __restrict__ step_ids,
    const float* __restrict__ pos_fts, const float* __restrict__ W_pos,
    const float* __restrict__ b_pos, const float* __restrict__ gamma,
    const float* __restrict__ beta, const float* __restrict__ step_tab,
    float* __restrict__ out)
{
    const int tid = threadIdx.x;
    const int w = tid >> 6, lane = tid & 63;

    // ---- interleave remap: physical blockIdx -> logical block id ----
    int blk;
    {
        const int p = blockIdx.x;
        if (p < NMAIN) {
            const int g = p / 13, s = p - g * 13;
            blk = (s < 8) ? (g * 8 + s) : (NBIN_BLKS + g * 5 + (s - 8));
        } else {
            blk = p;                        // tail blocks unchanged
        }
    }

    __shared__ int tvp_s[T], gvp_s[M], lens_s[T];
    __shared__ int code_s, cnt_s;
    __shared__ int list_s[3 * SEG];
    __shared__ int wcnt[3];
    __shared__ float w1[3], w2[3];

    if (blk < NBIN_BLKS) {
        // ================= bin path: (b, rank) =================
        const int b = blk >> 6, bin = blk & 63;

        if (tid < T) { tvp_s[tid] = tvp[b * T + tid]; lens_s[tid] = lens[b * T + tid]; }
        if (tid < M) gvp_s[tid] = gvp[b * M + tid];
        if (tid == 0) { code_s = -1; cnt_s = 0; }
        if (tid < 3) wcnt[tid] = 0;
        __syncthreads();

        // wave 0: rank the needed (mentioned && unvisited) codes
        if (tid < 64) {
            const int c = tid;
            bool mention = false;
            #pragma unroll 8
            for (int mm = 0; mm < M; ++mm) mention |= (gvp_s[mm] == c);
            bool vis = false;
            #pragma unroll 8
            for (int t = 0; t < T; ++t) vis |= (tvp_s[t] == c);
            const bool needed = mention && !vis;
            const unsigned long long mask = __ballot(needed);
            const int pre = __popcll(mask & ((1ull << c) - 1ull));
            if (needed && pre == bin) code_s = c;
        }
        __syncthreads();

        const int code = code_s;           // block-uniform
        if (code < 0) return;              // empty bin

        // unmasked count of cand == code
        const int* cb = cand + b * T * V;
        int local = 0;
        for (int i = tid; i < T * V; i += 192) local += (cb[i] == code);
        #pragma unroll
        for (int off = 32; off; off >>= 1) local += __shfl_xor(local, off);
        if (lane == 0) atomicAdd(&cnt_s, local);

        // member list (len-masked), wave w owns t = w, w+3, ...; fixed order
        int myn = 0;
        for (int t = w; t < T; t += 3) {
            const int cc = cb[t * V + lane];
            const bool ok = (lane < lens_s[t]) && (cc == code);
            const unsigned long long mk = __ballot(ok);
            if (ok) {
                const int pos = myn + __popcll(mk & ((1ull << lane) - 1ull));
                if (pos < SEG) list_s[w * SEG + pos] = t * V + lane;
            }
            myn += __popcll(mk);
        }
        if (lane == 0) wcnt[w] = min(myn, SEG);
        __syncthreads();

        float ax = 0.f, ay = 0.f, az = 0.f, aw = 0.f;
        const float* eb = emb + (size_t)b * T * V * H + tid * 4;
        for (int ww = 0; ww < 3; ++ww) {   // fixed segment order
            const int n = wcnt[ww];
            #pragma unroll 8
            for (int k = 0; k < n; ++k) {
                const int tvx = list_s[ww * SEG + k];
                const float4 x = *(const float4*)(eb + (size_t)tvx * H);
                ax += x.x; ay += x.y; az += x.z; aw += x.w;
            }
        }
        const float inv = 1.0f / fmaxf((float)cnt_s, 1.0f);
        ax *= inv; ay *= inv; az *= inv; aw *= inv;

        for (int m = 1; m < M; ++m)
            if (gvp_s[m] == code)
                epilogue(b, m, ax, ay, az, aw, pos_fts, W_pos, b_pos,
                         gamma, beta, step_ids, step_tab, out, w1, w2);
        return;
    }

    if (blk < NMAIN) {
        // ================= step path: (b, t) =================
        const int bt = blk - NBIN_BLKS;
        const int b = bt / T, t = bt - b * T;

        if (tid < T) tvp_s[tid] = tvp[b * T + tid];
        if (tid < M) gvp_s[tid] = gvp[b * M + tid];
        __syncthreads();

        const int c = tvp_s[t];
        int lt = -1;
        #pragma unroll 8
        for (int tt = 0; tt < T; ++tt) if (tvp_s[tt] == c) lt = tt;
        if (lt != t) return;               // another block owns this code

        bool any = false;
        #pragma unroll 8
        for (int m = 1; m < M; ++m) any |= (gvp_s[m] == c);
        if (!any) return;                  // no consumer

        const int len = lens[bt];
        const float* base = emb + (size_t)bt * V * H + tid * 4;
        float ax = 0.f, ay = 0.f, az = 0.f, aw = 0.f;
        int v = 0;
        for (; v + 16 <= len; v += 16) {
            #pragma unroll
            for (int u = 0; u < 16; ++u) {
                const float4 x = *(const float4*)(base + (size_t)(v + u) * H);
                ax += x.x; ay += x.y; az += x.z; aw += x.w;
            }
        }
        #pragma unroll 4
        for (; v < len; ++v) {
            const float4 x = *(const float4*)(base + (size_t)v * H);
            ax += x.x; ay += x.y; az += x.z; aw += x.w;
        }
        const float inv = 1.0f / (float)len;
        ax *= inv; ay *= inv; az *= inv; aw *= inv;

        for (int m = 1; m < M; ++m)
            if (gvp_s[m] == c)
                epilogue(b, m, ax, ay, az, aw, pos_fts, W_pos, b_pos,
                         gamma, beta, step_ids, step_tab, out, w1, w2);
        return;
    }

    // ================= catch-all path: one block per batch =================
    {
        const int b = blk - NMAIN;
        if (tid < M) gvp_s[tid] = gvp[b * M + tid];
        __syncthreads();
        for (int m = 0; m < M; ++m) {
            const int g = gvp_s[m];
            const bool handled = (m != 0) && (g >= 0) && (g < NCODE);
            if (!handled)
                epilogue(b, m, 0.f, 0.f, 0.f, 0.f, pos_fts, W_pos, b_pos,
                         gamma, beta, step_ids, step_tab, out, w1, w2);
        }
    }
}

// ---------------------------------------------------------------------------
extern "C" void kernel_launch(void* const* d_in, const int* in_sizes, int n_in,
                              void* d_out, int out_size, void* d_ws, size_t ws_size,
                              hipStream_t stream)
{
    const float* emb      = (const float*)d_in[2];
    const int*   vp_lens  = (const int*)d_in[3];
    const int*   tvp      = (const int*)d_in[4];
    const int*   cand     = (const int*)d_in[5];
    const int*   gvp      = (const int*)d_in[6];
    const int*   step_ids = (const int*)d_in[7];
    const float* pos_fts  = (const float*)d_in[8];
    const float* W_pos    = (const float*)d_in[10];
    const float* b_pos    = (const float*)d_in[11];
    const float* gamma    = (const float*)d_in[12];
    const float* beta     = (const float*)d_in[13];
    const float* step_tab = (const float*)d_in[14];
    float* out = (float*)d_out;

    fused_kernel<<<NMAIN + NTAIL, 192, 0, stream>>>(
        emb, vp_lens, cand, tvp, gvp, step_ids, pos_fts,
        W_pos, b_pos, gamma, beta, step_tab, out);
}